// Round 9
// baseline (1480.293 us; speedup 1.0000x reference)
//
#include <hip/hip_runtime.h>

#define H 22
#define EPS 1e-5f
#define SLOPE 0.01f
#define NT 256
#define NBLK 1024
#define WPB 4
#define NWAVES (NBLK * WPB)

typedef __attribute__((ext_vector_type(8))) _Float16 half8;
typedef __attribute__((ext_vector_type(4))) float f32x4;

#define MFMA(A, B, C) __builtin_amdgcn_mfma_f32_16x16x32_f16(A, B, C, 0, 0, 0)

__device__ __forceinline__ float leakyf(float u) { return u > 0.f ? u : SLOPE * u; }

// k/m mapping used CONSISTENTLY for all operand constructions:
// k(g,e) = 16*(e>>2) + 4*g + (e&3).  C-frag m at (tile,reg) = kmap(g, 4*tile+reg),
// so chained C->B repack is in-lane. Any deviation from the true HW k-map applies
// the same permutation to A and B and cancels in the contraction.
__device__ __forceinline__ int kmap(int g, int e) {
  return ((e >> 2) << 4) + (g << 2) + (e & 3);
}

// Build A-fragment of W (rows x cols row-major), M-tile at mbase, K-offset kbase.
// Out-of-range (m>=rows or k>=cols) -> 0 (handles 22->32 padding).
__device__ __forceinline__ half8 buildA(const float* __restrict__ W, int rows, int cols,
                                        int mbase, int kbase, int g) {
  int m = mbase + ((int)threadIdx.x & 15);
  half8 a;
#pragma unroll
  for (int e = 0; e < 8; e++) {
    int k = kbase + kmap(g, e);
    float v = (m < rows && k < cols) ? W[m * cols + k] : 0.f;
    a[e] = (_Float16)v;
  }
  return a;
}

// per-wave stats (s,q indexed by e: feature m = kmap(g,e)) -> block reduce -> atomics
__device__ __forceinline__ void commit_stats(float* s, float* q,
                                             float red[WPB][2 * H],
                                             float* __restrict__ accOut) {
  int lane = (int)threadIdx.x & 63, w = (int)threadIdx.x >> 6, g = lane >> 4;
#pragma unroll
  for (int r = 0; r < 8; r++) {
#pragma unroll
    for (int off = 1; off < 16; off <<= 1) {
      s[r] += __shfl_xor(s[r], off);
      q[r] += __shfl_xor(q[r], off);
    }
  }
  if ((lane & 15) == 0) {
#pragma unroll
    for (int r = 0; r < 8; r++) {
      int m = kmap(g, r);
      if (m < H) { red[w][m] = s[r]; red[w][H + m] = q[r]; }
    }
  }
  __syncthreads();
  if ((int)threadIdx.x < 2 * H) {
    float v = red[0][threadIdx.x] + red[1][threadIdx.x] +
              red[2][threadIdx.x] + red[3][threadIdx.x];
    atomicAdd(&accOut[threadIdx.x], v);
  }
}

// ---- proj: z0 = Wp @ x + bp -> bufT (f16 frag layout), stats(z0) -> acc stage 0
__global__ void __launch_bounds__(NT) proj_kernel(
    const float* __restrict__ x, const float* __restrict__ Wp,
    const float* __restrict__ bp, half8* __restrict__ bufT,
    float* __restrict__ acc0, int ntiles) {
  __shared__ float sBP[32];
  __shared__ float red[WPB][2 * H];
  int tid = threadIdx.x;
  if (tid < 32) sBP[tid] = (tid < H) ? bp[tid] : 0.f;
  __syncthreads();
  int lane = tid & 63, w = tid >> 6, g = lane >> 4, n = lane & 15;
  int wid = blockIdx.x * WPB + w;

  half8 A00 = buildA(Wp, H, 64, 0, 0, g);
  half8 A01 = buildA(Wp, H, 64, 0, 32, g);
  half8 A10 = buildA(Wp, H, 64, 16, 0, g);
  half8 A11 = buildA(Wp, H, 64, 16, 32, g);
  float bpv[8];
#pragma unroll
  for (int e = 0; e < 8; e++) bpv[e] = sBP[kmap(g, e)];

  float s[8], q[8];
#pragma unroll
  for (int e = 0; e < 8; e++) { s[e] = 0.f; q[e] = 0.f; }

  const float4* x4 = (const float4*)x;
  // 2-tile unroll: 8 independent x-loads in flight per iteration.
  for (int t = wid; t < ntiles; t += 2 * NWAVES) {
    int tt[2] = {t, t + NWAVES};
    float4 L[2][4];
#pragma unroll
    for (int u = 0; u < 2; u++) {
      size_t row = (size_t)tt[u] * 16 + n;
      L[u][0] = x4[row * 16 + g];
      L[u][1] = x4[row * 16 + 4 + g];
      L[u][2] = x4[row * 16 + 8 + g];
      L[u][3] = x4[row * 16 + 12 + g];
    }
#pragma unroll
    for (int u = 0; u < 2; u++) {
      half8 B0, B1;
      B0[0] = (_Float16)L[u][0].x; B0[1] = (_Float16)L[u][0].y;
      B0[2] = (_Float16)L[u][0].z; B0[3] = (_Float16)L[u][0].w;
      B0[4] = (_Float16)L[u][1].x; B0[5] = (_Float16)L[u][1].y;
      B0[6] = (_Float16)L[u][1].z; B0[7] = (_Float16)L[u][1].w;
      B1[0] = (_Float16)L[u][2].x; B1[1] = (_Float16)L[u][2].y;
      B1[2] = (_Float16)L[u][2].z; B1[3] = (_Float16)L[u][2].w;
      B1[4] = (_Float16)L[u][3].x; B1[5] = (_Float16)L[u][3].y;
      B1[6] = (_Float16)L[u][3].z; B1[7] = (_Float16)L[u][3].w;

      f32x4 c0 = {0.f, 0.f, 0.f, 0.f}, c1 = {0.f, 0.f, 0.f, 0.f};
      c0 = MFMA(A00, B0, c0); c0 = MFMA(A01, B1, c0);
      c1 = MFMA(A10, B0, c1); c1 = MFMA(A11, B1, c1);

      half8 zb;
#pragma unroll
      for (int e = 0; e < 8; e++) {
        float z = ((e < 4) ? c0[e & 3] : c1[e & 3]) + bpv[e];
        s[e] += z; q[e] += z * z;
        zb[e] = (_Float16)z;
      }
      bufT[(size_t)tt[u] * 64 + g * 16 + n] = zb;
    }
  }
  commit_stats(s, q, red, acc0);
}

// ---- per-tile bodies (all e-indices static after unroll) ----
__device__ __forceinline__ void bn0_tile(half8 zb, half8* __restrict__ dst,
                                         const half8& A0, const half8& A1,
                                         const float* aK, const float* cK,
                                         const float* b1v, float* s, float* q) {
  half8 hb;
#pragma unroll
  for (int e = 0; e < 8; e++)
    hb[e] = (_Float16)(aK[e] * (float)zb[e] + cK[e]);
  *dst = hb;
  f32x4 c0 = {0.f, 0.f, 0.f, 0.f}, c1 = {0.f, 0.f, 0.f, 0.f};
  c0 = MFMA(A0, hb, c0);
  c1 = MFMA(A1, hb, c1);
#pragma unroll
  for (int e = 0; e < 8; e++) {
    float z = ((e < 4) ? c0[e & 3] : c1[e & 3]) + b1v[e];
    s[e] += z; q[e] += z * z;
  }
}

__device__ __forceinline__ void p2_tile(half8 hb,
                                        const half8& A10, const half8& A11,
                                        const half8& A20, const half8& A21,
                                        const float* a1v, const float* b1v,
                                        const float* b2v, float* s, float* q) {
  f32x4 c0 = {0.f, 0.f, 0.f, 0.f}, c1 = {0.f, 0.f, 0.f, 0.f};
  c0 = MFMA(A10, hb, c0);
  c1 = MFMA(A11, hb, c1);
  half8 tb;
#pragma unroll
  for (int e = 0; e < 8; e++) {
    float c = (e < 4) ? c0[e & 3] : c1[e & 3];
    tb[e] = (_Float16)leakyf(a1v[e] * c + b1v[e]);
  }
  f32x4 d0 = {0.f, 0.f, 0.f, 0.f}, d1 = {0.f, 0.f, 0.f, 0.f};
  d0 = MFMA(A20, tb, d0);
  d1 = MFMA(A21, tb, d1);
#pragma unroll
  for (int e = 0; e < 8; e++) {
    float z = ((e < 4) ? d0[e & 3] : d1[e & 3]) + b2v[e];
    s[e] += z; q[e] += z * z;
  }
}

template <int LAST>
__device__ __forceinline__ void p3_tile(half8 hb, half8* __restrict__ dst,
                                        const half8& A10, const half8& A11,
                                        const half8& A20, const half8& A21,
                                        const half8& An0, const half8& An1,
                                        const float* a1v, const float* b1v,
                                        const float* a2v, const float* b2v,
                                        const float* auxv, float bo0,
                                        float* __restrict__ outp, int lane,
                                        float* s, float* q) {
  f32x4 c0 = {0.f, 0.f, 0.f, 0.f}, c1 = {0.f, 0.f, 0.f, 0.f};
  c0 = MFMA(A10, hb, c0);
  c1 = MFMA(A11, hb, c1);
  half8 tb;
#pragma unroll
  for (int e = 0; e < 8; e++) {
    float c = (e < 4) ? c0[e & 3] : c1[e & 3];
    tb[e] = (_Float16)leakyf(a1v[e] * c + b1v[e]);
  }
  f32x4 d0 = {0.f, 0.f, 0.f, 0.f}, d1 = {0.f, 0.f, 0.f, 0.f};
  d0 = MFMA(A20, tb, d0);
  d1 = MFMA(A21, tb, d1);
  float hn[8];
  half8 nb;
#pragma unroll
  for (int e = 0; e < 8; e++) {
    float d = (e < 4) ? d0[e & 3] : d1[e & 3];
    float hv = (float)hb[e];
    hn[e] = leakyf(hv + a2v[e] * d + b2v[e]);
    nb[e] = (_Float16)hn[e];
  }
  if (!LAST) {
    *dst = nb;
    f32x4 e0 = {0.f, 0.f, 0.f, 0.f}, e1 = {0.f, 0.f, 0.f, 0.f};
    e0 = MFMA(An0, nb, e0);
    e1 = MFMA(An1, nb, e1);
#pragma unroll
    for (int e = 0; e < 8; e++) {
      float z = ((e < 4) ? e0[e & 3] : e1[e & 3]) + auxv[e];
      s[e] += z; q[e] += z * z;
    }
  } else {
    float part = 0.f;
#pragma unroll
    for (int e = 0; e < 8; e++) part += auxv[e] * hn[e];
    part += __shfl_xor(part, 16);
    part += __shfl_xor(part, 32);
    if (lane < 16) outp[lane & 15] = part + bo0;
  }
}

// ---- bn0: h0 = a0*z0 + c0 (in place) ; stats of z1_0 = W1 h0 + b1
__global__ void __launch_bounds__(NT) bn0_kernel(
    half8* __restrict__ bufT, const float* __restrict__ accIn,
    float* __restrict__ accOut, const float* __restrict__ g0,
    const float* __restrict__ be0, const float* __restrict__ W1,
    const float* __restrict__ b1, int ntiles, float invN) {
  __shared__ float sA[32], sC[32], sB1[32];
  __shared__ float red[WPB][2 * H];
  int tid = threadIdx.x;
  if (tid < 32) {
    float a = 0.f, c = 0.f, bv = 0.f;
    if (tid < H) {
      float mu = accIn[tid] * invN;
      float var = accIn[H + tid] * invN - mu * mu;
      a = g0[tid] * rsqrtf(var + EPS);
      c = be0[tid] - a * mu;
      bv = b1[tid];
    }
    sA[tid] = a; sC[tid] = c; sB1[tid] = bv;
  }
  __syncthreads();
  int lane = tid & 63, w = tid >> 6, g = lane >> 4, n = lane & 15;
  int wid = blockIdx.x * WPB + w;
  int base = g * 16 + n;

  half8 A0 = buildA(W1, H, H, 0, 0, g), A1 = buildA(W1, H, H, 16, 0, g);
  float aK[8], cK[8], b1v[8];
#pragma unroll
  for (int e = 0; e < 8; e++) {
    int m = kmap(g, e);
    aK[e] = sA[m]; cK[e] = sC[m]; b1v[e] = sB1[m];
  }
  float s[8], q[8];
#pragma unroll
  for (int e = 0; e < 8; e++) { s[e] = 0.f; q[e] = 0.f; }

  for (int t = wid; t < ntiles; t += 4 * NWAVES) {
    half8 z0 = bufT[(size_t)t * 64 + base];
    half8 z1 = bufT[(size_t)(t + NWAVES) * 64 + base];
    half8 z2 = bufT[(size_t)(t + 2 * NWAVES) * 64 + base];
    half8 z3 = bufT[(size_t)(t + 3 * NWAVES) * 64 + base];
    bn0_tile(z0, &bufT[(size_t)t * 64 + base], A0, A1, aK, cK, b1v, s, q);
    bn0_tile(z1, &bufT[(size_t)(t + NWAVES) * 64 + base], A0, A1, aK, cK, b1v, s, q);
    bn0_tile(z2, &bufT[(size_t)(t + 2 * NWAVES) * 64 + base], A0, A1, aK, cK, b1v, s, q);
    bn0_tile(z3, &bufT[(size_t)(t + 3 * NWAVES) * 64 + base], A0, A1, aK, cK, b1v, s, q);
  }
  commit_stats(s, q, red, accOut);
}

// ---- P2: t = leaky(a1*(W1 h) + b1f) ; z2 = W2 t + b2 (raw) ; stats(z2)
__global__ void __launch_bounds__(NT) p2_kernel(
    const half8* __restrict__ bufT, const float* __restrict__ accIn,
    float* __restrict__ accOut, const float* __restrict__ g1,
    const float* __restrict__ be1, const float* __restrict__ W1,
    const float* __restrict__ b1, const float* __restrict__ W2,
    const float* __restrict__ b2, int ntiles, float invN) {
  __shared__ float sA1[32], sB1F[32], sB2[32];
  __shared__ float red[WPB][2 * H];
  int tid = threadIdx.x;
  if (tid < 32) {
    float a = 0.f, bf = 0.f, bv = 0.f;
    if (tid < H) {
      float mu = accIn[tid] * invN;
      float var = accIn[H + tid] * invN - mu * mu;
      a = g1[tid] * rsqrtf(var + EPS);
      bf = a * b1[tid] + be1[tid] - a * mu;
      bv = b2[tid];
    }
    sA1[tid] = a; sB1F[tid] = bf; sB2[tid] = bv;
  }
  __syncthreads();
  int lane = tid & 63, w = tid >> 6, g = lane >> 4, n = lane & 15;
  int wid = blockIdx.x * WPB + w;
  int base = g * 16 + n;

  half8 A10 = buildA(W1, H, H, 0, 0, g), A11 = buildA(W1, H, H, 16, 0, g);
  half8 A20 = buildA(W2, H, H, 0, 0, g), A21 = buildA(W2, H, H, 16, 0, g);
  float a1v[8], b1v[8], b2v[8];
#pragma unroll
  for (int e = 0; e < 8; e++) {
    int m = kmap(g, e);
    a1v[e] = sA1[m]; b1v[e] = sB1F[m]; b2v[e] = sB2[m];
  }
  float s[8], q[8];
#pragma unroll
  for (int e = 0; e < 8; e++) { s[e] = 0.f; q[e] = 0.f; }

  for (int t = wid; t < ntiles; t += 4 * NWAVES) {
    half8 h0 = bufT[(size_t)t * 64 + base];
    half8 h1 = bufT[(size_t)(t + NWAVES) * 64 + base];
    half8 h2 = bufT[(size_t)(t + 2 * NWAVES) * 64 + base];
    half8 h3 = bufT[(size_t)(t + 3 * NWAVES) * 64 + base];
    p2_tile(h0, A10, A11, A20, A21, a1v, b1v, b2v, s, q);
    p2_tile(h1, A10, A11, A20, A21, a1v, b1v, b2v, s, q);
    p2_tile(h2, A10, A11, A20, A21, a1v, b1v, b2v, s, q);
    p2_tile(h3, A10, A11, A20, A21, a1v, b1v, b2v, s, q);
  }
  commit_stats(s, q, red, accOut);
}

// ---- P3: recompute t, z2 ; h' = leaky(h + a2*(W2 t) + b2f) ; store h' ;
//          fused next-layer z1 stats (raw) or final output when LAST
template <int LAST>
__global__ void __launch_bounds__(NT) p3_kernel(
    half8* __restrict__ bufT, const float* __restrict__ accZ1,
    const float* __restrict__ accZ2, float* __restrict__ accOut,
    const float* __restrict__ g1, const float* __restrict__ be1,
    const float* __restrict__ g2, const float* __restrict__ be2,
    const float* __restrict__ W1, const float* __restrict__ b1,
    const float* __restrict__ W2, const float* __restrict__ b2,
    const float* __restrict__ W1n, const float* __restrict__ b1n,
    const float* __restrict__ Wo, const float* __restrict__ bo,
    float* __restrict__ out, int ntiles, float invN) {
  __shared__ float sA1[32], sB1F[32], sA2[32], sB2F[32], sAux[32];
  __shared__ float red[WPB][2 * H];
  int tid = threadIdx.x;
  if (tid < 32) {
    float a1 = 0.f, b1f = 0.f, a2 = 0.f, b2f = 0.f, aux = 0.f;
    if (tid < H) {
      float mu1 = accZ1[tid] * invN;
      float v1 = accZ1[H + tid] * invN - mu1 * mu1;
      a1 = g1[tid] * rsqrtf(v1 + EPS);
      b1f = a1 * b1[tid] + be1[tid] - a1 * mu1;
      float mu2 = accZ2[tid] * invN;
      float v2 = accZ2[H + tid] * invN - mu2 * mu2;
      a2 = g2[tid] * rsqrtf(v2 + EPS);
      b2f = a2 * b2[tid] + be2[tid] - a2 * mu2;
      aux = LAST ? Wo[tid] : b1n[tid];
    }
    sA1[tid] = a1; sB1F[tid] = b1f; sA2[tid] = a2; sB2F[tid] = b2f; sAux[tid] = aux;
  }
  __syncthreads();
  int lane = tid & 63, w = tid >> 6, g = lane >> 4, n = lane & 15;
  int wid = blockIdx.x * WPB + w;
  int base = g * 16 + n;

  half8 A10 = buildA(W1, H, H, 0, 0, g), A11 = buildA(W1, H, H, 16, 0, g);
  half8 A20 = buildA(W2, H, H, 0, 0, g), A21 = buildA(W2, H, H, 16, 0, g);
  half8 An0 = {}, An1 = {};
  if (!LAST) { An0 = buildA(W1n, H, H, 0, 0, g); An1 = buildA(W1n, H, H, 16, 0, g); }
  float a1v[8], b1v[8], a2v[8], b2v[8], auxv[8];
#pragma unroll
  for (int e = 0; e < 8; e++) {
    int m = kmap(g, e);
    a1v[e] = sA1[m]; b1v[e] = sB1F[m]; a2v[e] = sA2[m]; b2v[e] = sB2F[m]; auxv[e] = sAux[m];
  }
  float s[8], q[8];
#pragma unroll
  for (int e = 0; e < 8; e++) { s[e] = 0.f; q[e] = 0.f; }
  float bo0 = LAST ? bo[0] : 0.f;

  for (int t = wid; t < ntiles; t += 4 * NWAVES) {
    half8 h0 = bufT[(size_t)t * 64 + base];
    half8 h1 = bufT[(size_t)(t + NWAVES) * 64 + base];
    half8 h2 = bufT[(size_t)(t + 2 * NWAVES) * 64 + base];
    half8 h3 = bufT[(size_t)(t + 3 * NWAVES) * 64 + base];
    p3_tile<LAST>(h0, &bufT[(size_t)t * 64 + base], A10, A11, A20, A21, An0, An1,
                  a1v, b1v, a2v, b2v, auxv, bo0, out + (size_t)t * 16, lane, s, q);
    p3_tile<LAST>(h1, &bufT[(size_t)(t + NWAVES) * 64 + base], A10, A11, A20, A21,
                  An0, An1, a1v, b1v, a2v, b2v, auxv, bo0,
                  out + (size_t)(t + NWAVES) * 16, lane, s, q);
    p3_tile<LAST>(h2, &bufT[(size_t)(t + 2 * NWAVES) * 64 + base], A10, A11, A20, A21,
                  An0, An1, a1v, b1v, a2v, b2v, auxv, bo0,
                  out + (size_t)(t + 2 * NWAVES) * 16, lane, s, q);
    p3_tile<LAST>(h3, &bufT[(size_t)(t + 3 * NWAVES) * 64 + base], A10, A11, A20, A21,
                  An0, An1, a1v, b1v, a2v, b2v, auxv, bo0,
                  out + (size_t)(t + 3 * NWAVES) * 16, lane, s, q);
  }
  if (!LAST) commit_stats(s, q, red, accOut);
}

extern "C" void kernel_launch(void* const* d_in, const int* in_sizes, int n_in,
                              void* d_out, int out_size, void* d_ws, size_t ws_size,
                              hipStream_t stream) {
  const float* x    = (const float*)d_in[0];
  const float* Wp   = (const float*)d_in[1];
  const float* bp   = (const float*)d_in[2];
  const float* g0   = (const float*)d_in[3];
  const float* be0  = (const float*)d_in[4];
  const float* W1s  = (const float*)d_in[5];
  const float* b1s  = (const float*)d_in[6];
  const float* g1s  = (const float*)d_in[7];
  const float* be1s = (const float*)d_in[8];
  const float* W2s  = (const float*)d_in[9];
  const float* b2s  = (const float*)d_in[10];
  const float* g2s  = (const float*)d_in[11];
  const float* be2s = (const float*)d_in[12];
  const float* Wo   = (const float*)d_in[13];
  const float* bo   = (const float*)d_in[14];

  int N = in_sizes[0] / 64;  // 1048576
  int ntiles = N / 16;       // 65536
  float invN = 1.0f / (float)N;

  half8* bufT = (half8*)d_ws;                         // 64 MB f16 fragment buffer
  float* acc = (float*)(bufT + (size_t)ntiles * 64);  // 33 stages x 44 floats

  hipMemsetAsync(acc, 0, 33 * 2 * H * sizeof(float), stream);

  dim3 grid(NBLK), block(NT);
  const int HH = H * H;

  proj_kernel<<<grid, block, 0, stream>>>(x, Wp, bp, bufT, acc, ntiles);
  bn0_kernel<<<grid, block, 0, stream>>>(bufT, acc, acc + 44, g0, be0, W1s, b1s,
                                         ntiles, invN);

  for (int k = 0; k < 16; k++) {
    p2_kernel<<<grid, block, 0, stream>>>(
        bufT, acc + (2 * k + 1) * 44, acc + (2 * k + 2) * 44,
        g1s + k * H, be1s + k * H, W1s + k * HH, b1s + k * H,
        W2s + k * HH, b2s + k * H, ntiles, invN);
    if (k < 15) {
      p3_kernel<0><<<grid, block, 0, stream>>>(
          bufT, acc + (2 * k + 1) * 44, acc + (2 * k + 2) * 44, acc + (2 * k + 3) * 44,
          g1s + k * H, be1s + k * H, g2s + k * H, be2s + k * H,
          W1s + k * HH, b1s + k * H, W2s + k * HH, b2s + k * H,
          W1s + (k + 1) * HH, b1s + (k + 1) * H, nullptr, nullptr, nullptr,
          ntiles, invN);
    } else {
      p3_kernel<1><<<grid, block, 0, stream>>>(
          bufT, acc + (2 * k + 1) * 44, acc + (2 * k + 2) * 44, nullptr,
          g1s + k * H, be1s + k * H, g2s + k * H, be2s + k * H,
          W1s + k * HH, b1s + k * H, W2s + k * HH, b2s + k * H,
          W1s + k * HH, b1s + k * H, Wo, bo, (float*)d_out, ntiles, invN);
    }
  }
}